// Round 18
// baseline (272.360 us; speedup 1.0000x reference)
//
#include <hip/hip_runtime.h>
#include <hip/hip_bf16.h>

typedef __attribute__((ext_vector_type(8))) short short8;
typedef __attribute__((ext_vector_type(4))) short short4v;
typedef __attribute__((ext_vector_type(4))) float floatx4;

#define LOG2E 1.4426950408889634f

static __device__ __forceinline__ short f2bf(float f) {
    unsigned int u = __float_as_uint(f);
    unsigned int r = u + 0x7FFFu + ((u >> 16) & 1u);
    return (short)(r >> 16);
}
static __device__ __forceinline__ float bf2f(short s) {
    return __uint_as_float(((unsigned int)(unsigned short)s) << 16);
}

static __device__ __forceinline__ void load_lds16(const void* g, void* l) {
    __builtin_amdgcn_global_load_lds(
        (const __attribute__((address_space(1))) unsigned int*)g,
        (__attribute__((address_space(3))) unsigned int*)l, 16, 0, 0);
}

// ------- fused prep: cast x (f32->bf16) + transpose W_qkv + transpose W_out -------
__global__ __launch_bounds__(256) void prep_kernel(
    const float* __restrict__ x, short* __restrict__ Xb,
    const float* __restrict__ Wqkv, short* __restrict__ Wqkvt,
    const float* __restrict__ Wout, short* __restrict__ Woutt) {
    const int blk = blockIdx.x;
    if (blk < 4096) {
        const int i = blk * 256 + threadIdx.x;
        const float4 v0 = *(const float4*)(x + (size_t)i * 8);
        const float4 v1 = *(const float4*)(x + (size_t)i * 8 + 4);
        short8 s;
        s[0] = f2bf(v0.x); s[1] = f2bf(v0.y); s[2] = f2bf(v0.z); s[3] = f2bf(v0.w);
        s[4] = f2bf(v1.x); s[5] = f2bf(v1.y); s[6] = f2bf(v1.z); s[7] = f2bf(v1.w);
        *(short8*)(Xb + (size_t)i * 8) = s;
        return;
    }
    __shared__ float tile[32][33];
    const float* in;
    short* out;
    int R, C, bx, by;
    if (blk < 16384) {
        const int local = blk - 4096;
        in = Wqkv; out = Wqkvt; R = 2048; C = 6144;
        bx = local % 192; by = local / 192;
    } else {
        const int local = blk - 16384;
        in = Wout; out = Woutt; R = 2048; C = 2048;
        bx = local % 64; by = local / 64;
    }
    const int tx = threadIdx.x & 31, ty = threadIdx.x >> 5;
    const int xx = bx * 32 + tx;
    const int y0 = by * 32;
#pragma unroll
    for (int j = 0; j < 4; ++j)
        tile[ty + j * 8][tx] = in[(size_t)(y0 + ty + j * 8) * C + xx];
    __syncthreads();
#pragma unroll
    for (int j = 0; j < 4; ++j)
        out[(size_t)(bx * 32 + ty + j * 8) * R + y0 + tx] =
            f2bf(tile[tx][ty + j * 8]);
}

// ---- GEMM v5: BM=256 x BN=128, BK=64, 4 waves, per-wave 128x64 (128 AGPR) ----
// A double-buffered (64 KB) + B single-buffered (16 KB) = 80 KB LDS.
// Per K-step: issue A(t+1)->other buf | read bfr | barA(lgkm only) |
// issue B(t+1) | stream af + 64 MFMA | __syncthreads (drains DMA).
// XOR chunk swizzle (physical = logical ^ (row&7)) on staging and reads.
template <int EPI>
__global__ __launch_bounds__(256) void gemm256_kernel(
    const short* __restrict__ A, const short* __restrict__ Bt,
    const float* __restrict__ bias, float* __restrict__ Cf,
    short* __restrict__ Qb, short* __restrict__ Kb, short* __restrict__ Vt,
    int M, int N, int K, int gx) {
    __shared__ __align__(16) short SMEM[40960];   // 80 KB
    // Abuf0 @0, Abuf1 @16384, Bbuf @32768 (shorts)

    const int tid = threadIdx.x;
    const int lane = tid & 63, wave = tid >> 6;
    const int wm = wave >> 1, wn = wave & 1;
    const int lr = lane & 15, lk = lane >> 4;
    const int swl = lr & 7;

    const int nwg = gridDim.x;
    const int id = blockIdx.x;
    const int swz = (id & 7) * (nwg >> 3) + (id >> 3);
    const int bx = swz % gx, by = swz / gx;
    const int bm0 = by * 256, bn0 = bx * 128;

    // staging bases: g = j*256+tid; row = g>>3, chunk = (g&7)^(row&7)
    const int g0 = tid;
    const int row0 = g0 >> 3;
    const int ch0 = (g0 & 7) ^ (row0 & 7);
    const char* aS0 = (const char*)(A + (size_t)(bm0 + row0) * K + ch0 * 8);
    const char* bS0 = (const char*)(Bt + (size_t)(bn0 + row0) * K + ch0 * 8);
    const size_t jstride = (size_t)32 * K * 2;   // +256 g -> +32 rows

    floatx4 acc[8][4];
#pragma unroll
    for (int m = 0; m < 8; ++m)
#pragma unroll
        for (int n = 0; n < 4; ++n) acc[m][n] = (floatx4){0.f, 0.f, 0.f, 0.f};

    const int nt = K >> 6;

    // prologue: stage A(0)->Abuf0, B(0)->Bbuf
#pragma unroll
    for (int j = 0; j < 8; ++j)
        load_lds16(aS0 + (size_t)j * jstride, &SMEM[(j * 256 + tid) * 8]);
#pragma unroll
    for (int j = 0; j < 4; ++j)
        load_lds16(bS0 + (size_t)j * jstride, &SMEM[32768 + (j * 256 + tid) * 8]);
    __syncthreads();

    for (int t = 0; t < nt; ++t) {
        const int a = t & 1;
        const size_t ko = (size_t)(t + 1) * 128;   // next K-step byte offset

        if (t + 1 < nt) {  // A(t+1) -> other A buffer; flies the whole iteration
            const int ab = (a ^ 1) * 16384;
#pragma unroll
            for (int j = 0; j < 8; ++j)
                load_lds16(aS0 + (size_t)j * jstride + ko,
                           &SMEM[ab + (j * 256 + tid) * 8]);
        }

        // B fragments for this K-step
        short8 bfr[4][2];
#pragma unroll
        for (int n = 0; n < 4; ++n)
#pragma unroll
            for (int ks = 0; ks < 2; ++ks)
                bfr[n][ks] = *(const short8*)
                    &SMEM[32768 + (wn * 64 + n * 16 + lr) * 64 +
                          (((ks * 4 + lk) ^ swl) * 8)];

        // barA: all waves' B reads retired; vmcnt NOT drained (A-DMA keeps flying)
        __builtin_amdgcn_sched_barrier(0);
        asm volatile("s_waitcnt lgkmcnt(0)" ::: "memory");
        __builtin_amdgcn_sched_barrier(0);
        __builtin_amdgcn_s_barrier();

        if (t + 1 < nt) {  // B(t+1): overwrites Bbuf; flies over the MFMA phase
#pragma unroll
            for (int j = 0; j < 4; ++j)
                load_lds16(bS0 + (size_t)j * jstride + ko,
                           &SMEM[32768 + (j * 256 + tid) * 8]);
        }

        // stream A fragments + MFMA (reads Abuf[a], not being overwritten)
        const short* Ac = SMEM + a * 16384;
        __builtin_amdgcn_s_setprio(1);
#pragma unroll
        for (int m = 0; m < 8; ++m) {
            short8 a0 = *(const short8*)
                &Ac[(wm * 128 + m * 16 + lr) * 64 + ((lk ^ swl) * 8)];
            short8 a1 = *(const short8*)
                &Ac[(wm * 128 + m * 16 + lr) * 64 + (((4 + lk) ^ swl) * 8)];
#pragma unroll
            for (int n = 0; n < 4; ++n) {
                acc[m][n] = __builtin_amdgcn_mfma_f32_16x16x32_bf16(
                    a0, bfr[n][0], acc[m][n], 0, 0, 0);
                acc[m][n] = __builtin_amdgcn_mfma_f32_16x16x32_bf16(
                    a1, bfr[n][1], acc[m][n], 0, 0, 0);
            }
        }
        __builtin_amdgcn_s_setprio(0);

        __syncthreads();  // drains A(t+1)+B(t+1) DMA; retires af reads
    }

    // ---- epilogue ----
    if (EPI == 1) {
#pragma unroll
        for (int m = 0; m < 8; ++m)
#pragma unroll
            for (int n = 0; n < 4; ++n)
#pragma unroll
                for (int r = 0; r < 4; ++r) {
                    const int row = bm0 + wm * 128 + m * 16 + lk * 4 + r;
                    const int col = bn0 + wn * 64 + n * 16 + lr;
                    Cf[(size_t)row * N + col] = acc[m][n][r] + bias[col];
                }
    } else {
        const int sec = bn0 >> 11;           // 0=Q 1=K 2=V, uniform per block
        if (sec == 2) {
            // V: transpose through LDS, then coalesced 16B writes to Vt[dq][s]
            short* Vtile = SMEM;             // [128][264] = 67.6 KB (SMEM dead)
#pragma unroll
            for (int m = 0; m < 8; ++m)
#pragma unroll
                for (int n = 0; n < 4; ++n)
#pragma unroll
                    for (int r = 0; r < 4; ++r) {
                        const int lrow = wm * 128 + m * 16 + lk * 4 + r;  // s-local
                        const int c = wn * 64 + n * 16 + lr;              // dq
                        const float val = acc[m][n][r] + bias[bn0 + c];
                        Vtile[c * 264 + lrow] = f2bf(val);
                    }
            __syncthreads();
            const int b = bm0 >> 11, s0b = bm0 & 2047;
            const int h = (bn0 >> 7) & 15;
            short* Vbase = Vt + (((size_t)(b * 16 + h)) * 128) * 2048 + s0b;
#pragma unroll
            for (int j = 0; j < 16; ++j) {
                const int c = tid + 256 * j;       // 0..4095
                const int dq = c >> 5;
                const int sOff = (c & 31) * 8;
                *(short8*)&Vbase[(size_t)dq * 2048 + sOff] =
                    *(const short8*)&Vtile[dq * 264 + sOff];
            }
        } else {
            short* T = (sec == 0) ? Qb : Kb;
#pragma unroll
            for (int m = 0; m < 8; ++m)
#pragma unroll
                for (int n = 0; n < 4; ++n)
#pragma unroll
                    for (int r = 0; r < 4; ++r) {
                        const int row = bm0 + wm * 128 + m * 16 + lk * 4 + r;
                        const int col = bn0 + wn * 64 + n * 16 + lr;
                        const float val = acc[m][n][r] + bias[col];
                        const int h = (col >> 7) & 15, dq = col & 127;
                        const int b = row >> 11, s = row & 2047;
                        T[(((size_t)(b * 16 + h)) * 2048 + s) * 128 + dq] = f2bf(val);
                    }
        }
    }
}

// ------- RoPE, vectorized: 4 (t1,t2) pairs per thread via short4 loads -------
__global__ void rope_kernel(short* __restrict__ Qb, short* __restrict__ Kb,
                            const int* __restrict__ pos, int total4) {
    int i = blockIdx.x * blockDim.x + threadIdx.x;
    short* T = Qb;
    int j = i;
    float g = 0.08838834764831845f * LOG2E;   // folded into Q only
    if (i >= total4) { T = Kb; j = i - total4; g = 1.0f; }
    if (j >= total4) return;
    const int ih0 = (j & 15) * 4;
    const int s = (j >> 4) & 2047;
    const size_t base = ((size_t)(j >> 4)) * 128 + ih0;
    short4v a = *(const short4v*)&T[base];
    short4v b = *(const short4v*)&T[base + 64];
    const float p = (float)pos[s];
    short4v ra, rb;
#pragma unroll
    for (int k = 0; k < 4; ++k) {
        const float ang = p * exp2f((float)(ih0 + k) * (-13.287712379549449f / 64.0f));
        float sn, cs;
        __sincosf(ang, &sn, &cs);
        sn *= g; cs *= g;
        const float t1 = bf2f(a[k]), t2 = bf2f(b[k]);
        ra[k] = f2bf(t1 * cs - t2 * sn);
        rb[k] = f2bf(t1 * sn + t2 * cs);
    }
    *(short4v*)&T[base] = ra;
    *(short4v*)&T[base + 64] = rb;
}

// ---------------- causal flash attention v8: QBLK=128, 8 waves ----------------
__global__ __launch_bounds__(512) void attn_kernel(
    const short* __restrict__ Qb, const short* __restrict__ Kb,
    const short* __restrict__ Vt, short* __restrict__ Ob) {
    const int f = blockIdx.x;                    // 512 blocks
    const int xcd = f & 7;
    const int rank = f >> 3;
    const int s_idx = (rank < 32) ? rank : 95 - rank;
    const int qt = 15 - (s_idx >> 2);
    const int bh = xcd * 4 + (s_idx & 3);
    const int tid = threadIdx.x;
    const int wave = tid >> 6, lane = tid & 63;
    const int lr = lane & 15, lk = lane >> 4;
    const int q0 = qt * 128;
    const short* Qh = Qb + (size_t)bh * 2048 * 128;
    const short* Kh = Kb + (size_t)bh * 2048 * 128;
    const short* Vh = Vt + (size_t)bh * 128 * 2048;

    __shared__ __align__(16) short Ks[64 * 128];
    __shared__ __align__(16) short Vs[128 * 64];
    __shared__ __align__(16) short Ps[8][16][72];

    const int c0 = tid, c1 = tid + 512;
    const int rK0 = c0 >> 4, rK1 = c1 >> 4;
    const int rV0 = c0 >> 3, rV1 = c1 >> 3;
    const char* srcK0 = (const char*)Kh + (size_t)rK0 * 256 + (((c0 & 15) ^ (rK0 & 7)) * 16);
    const char* srcK1 = (const char*)Kh + (size_t)rK1 * 256 + (((c1 & 15) ^ (rK1 & 7)) * 16);
    const char* srcV0 = (const char*)Vh + (size_t)rV0 * 4096 + (((c0 & 7) ^ (rV0 & 7)) * 16);
    const char* srcV1 = (const char*)Vh + (size_t)rV1 * 4096 + (((c1 & 7) ^ (rV1 & 7)) * 16);
    char* dK0 = (char*)Ks + c0 * 16;
    char* dK1 = (char*)Ks + c1 * 16;
    char* dV0 = (char*)Vs + c0 * 16;
    char* dV1 = (char*)Vs + c1 * 16;

    short8 qf[4];
#pragma unroll
    for (int kc = 0; kc < 4; ++kc)
        qf[kc] = *(const short8*)&Qh[(size_t)(q0 + wave * 16 + lr) * 128 + kc * 32 + lk * 8];

    floatx4 o[8];
#pragma unroll
    for (int d = 0; d < 8; ++d) o[d] = (floatx4){0.f, 0.f, 0.f, 0.f};
    float mrow[4], lrow[4];
#pragma unroll
    for (int r = 0; r < 4; ++r) { mrow[r] = -3.0e38f; lrow[r] = 0.f; }

    const int nkt = 2 * qt + 2;
    const int swzk = (lr & 7) << 3;

    load_lds16(srcK0, dK0);
    load_lds16(srcK1, dK1);
    load_lds16(srcV0, dV0);
    load_lds16(srcV1, dV1);
    __syncthreads();

    for (int t = 0; t < nkt; ++t) {
        const int s0 = t * 64;
        const bool active = !(t == nkt - 1 && wave < 4);

        floatx4 sv[4];
        if (active) {
            __builtin_amdgcn_s_setprio(1);
#pragma unroll
            for (int nt = 0; nt < 4; ++nt) {
                floatx4 a = (floatx4){0.f, 0.f, 0.f, 0.f};
#pragma unroll
                for (int kc = 0; kc < 4; ++kc) {
                    short8 kf = *(const short8*)
                        &Ks[(nt * 16 + lr) * 128 + ((kc * 32 + lk * 8) ^ swzk)];
                    a = __builtin_amdgcn_mfma_f32_16x16x32_bf16(qf[kc], kf, a, 0, 0, 0);
                }
                sv[nt] = a;
            }
            __builtin_amdgcn_s_setprio(0);
        }

        __syncthreads();
        if (t + 1 < nkt) {
            const size_t offK = (size_t)(t + 1) * 16384;
            load_lds16(srcK0 + offK, dK0);
            load_lds16(srcK1 + offK, dK1);
        }

        if (active) {
            if (t >= nkt - 2) {
#pragma unroll
                for (int nt = 0; nt < 4; ++nt)
#pragma unroll
                    for (int r = 0; r < 4; ++r) {
                        const int col = s0 + nt * 16 + lr;
                        const int row = q0 + wave * 16 + lk * 4 + r;
                        if (col > row) sv[nt][r] = -3.0e38f;
                    }
            }

            float tm[4];
#pragma unroll
            for (int r = 0; r < 4; ++r) {
                float v = fmaxf(fmaxf(sv[0][r], sv[1][r]), fmaxf(sv[2][r], sv[3][r]));
                v = fmaxf(v, __shfl_xor(v, 1));
                v = fmaxf(v, __shfl_xor(v, 2));
                v = fmaxf(v, __shfl_xor(v, 4));
                v = fmaxf(v, __shfl_xor(v, 8));
                tm[r] = v;
            }

            const bool ok = (tm[0] <= mrow[0] + 8.f) && (tm[1] <= mrow[1] + 8.f) &&
                            (tm[2] <= mrow[2] + 8.f) && (tm[3] <= mrow[3] + 8.f);
            if (!__all(ok)) {
                float alpha[4];
#pragma unroll
                for (int r = 0; r < 4; ++r) {
                    const float mn = fmaxf(mrow[r], tm[r]);
                    alpha[r] = exp2f(mrow[r] - mn);
                    mrow[r] = mn;
                    lrow[r] *= alpha[r];
                }
#pragma unroll
                for (int d = 0; d < 8; ++d)
#pragma unroll
                    for (int r = 0; r < 4; ++r) o[d][r] *= alpha[r];
            }

#pragma unroll
            for (int r = 0; r < 4; ++r) {
                float rs = 0.f;
#pragma unroll
                for (int nt = 0; nt < 4; ++nt) {
                    const float p = exp2f(sv[nt][r] - mrow[r]);
                    sv[nt][r] = p;
                    rs += p;
                }
                lrow[r] += rs;
            }
#pragma unroll
            for (int nt = 0; nt < 4; ++nt)
#pragma unroll
                for (int r = 0; r < 4; ++r)
                    Ps[wave][lk * 4 + r][nt * 16 + lr] =
                        (short)(__float_as_uint(sv[nt][r]) >> 16);

            __builtin_amdgcn_s_setprio(1);
#pragma unroll
            for (int kc = 0; kc < 2; ++kc) {
                short8 pf = *(const short8*)&Ps[wave][lr][kc * 32 + lk * 8];
#pragma unroll
                for (int d = 0; d < 8; ++d) {
                    short8 vf = *(const short8*)
                        &Vs[(d * 16 + lr) * 64 + ((kc * 32 + lk * 8) ^ swzk)];
                    o[d] = __builtin_amdgcn_mfma_f32_16x16x32_bf16(pf, vf, o[d], 0, 0, 0);
                }
            }
            __builtin_amdgcn_s_setprio(0);
        }

        if (t + 1 < nkt) {
            __syncthreads();
            const size_t offV = (size_t)(t + 1) * 128;
            load_lds16(srcV0 + offV, dV0);
            load_lds16(srcV1 + offV, dV1);
        }
    }

    // ---- epilogue ----
    float linv[4];
#pragma unroll
    for (int r = 0; r < 4; ++r) {
        float l = lrow[r];
        l += __shfl_xor(l, 1);
        l += __shfl_xor(l, 2);
        l += __shfl_xor(l, 4);
        l += __shfl_xor(l, 8);
        linv[r] = 1.0f / l;
    }
    const int b = bh >> 4, h = bh & 15;
#pragma unroll
    for (int d = 0; d < 8; ++d)
#pragma unroll
        for (int r = 0; r < 4; ++r) {
            const int srow = q0 + wave * 16 + lk * 4 + r;
            const float val = o[d][r] * linv[r];
            Ob[((size_t)(b * 2048 + srow)) * 2048 + h * 128 + d * 16 + lr] = f2bf(val);
        }
}

extern "C" void kernel_launch(void* const* d_in, const int* in_sizes, int n_in,
                              void* d_out, int out_size, void* d_ws, size_t ws_size,
                              hipStream_t stream) {
    const float* x = (const float*)d_in[0];
    const int* rope_pos = (const int*)d_in[1];
    const float* W_qkv = (const float*)d_in[2];
    const float* b_qkv = (const float*)d_in[3];
    const float* W_out = (const float*)d_in[4];
    const float* b_out = (const float*)d_in[5];
    float* out = (float*)d_out;

    char* ws = (char*)d_ws;
    short* Wqkvt = (short*)ws;                                   // 25165824 B
    short* Woutt = (short*)(ws + 25165824);                      // 8388608 B
    short* Qb = (short*)(ws + 25165824 + 8388608);               // 8388608 B each
    short* Kb = Qb + 8388608;
    short* Vt = Kb + 8388608;
    short* Attn = Vt + 8388608;
    short* Xb = Attn;  // alias: Xb dead before attn_kernel writes Attn

    prep_kernel<<<20480, 256, 0, stream>>>(x, Xb, W_qkv, Wqkvt, W_out, Woutt);
    gemm256_kernel<0><<<768, 256, 0, stream>>>(
        Xb, Wqkvt, b_qkv, nullptr, Qb, Kb, Vt, 4096, 6144, 2048, 48);
    rope_kernel<<<8192, 256, 0, stream>>>(Qb, Kb, rope_pos, 1048576);
    attn_kernel<<<512, 512, 0, stream>>>(Qb, Kb, Vt, Attn);
    gemm256_kernel<1><<<256, 256, 0, stream>>>(
        Attn, Woutt, b_out, out, nullptr, nullptr, nullptr, 4096, 2048, 2048, 16);
}

// Round 19
// 253.849 us; speedup vs baseline: 1.0729x; 1.0729x over previous
//
#include <hip/hip_runtime.h>
#include <hip/hip_bf16.h>

typedef __attribute__((ext_vector_type(8))) short short8;
typedef __attribute__((ext_vector_type(4))) short short4v;
typedef __attribute__((ext_vector_type(4))) float floatx4;

#define LOG2E 1.4426950408889634f

static __device__ __forceinline__ short f2bf(float f) {
    unsigned int u = __float_as_uint(f);
    unsigned int r = u + 0x7FFFu + ((u >> 16) & 1u);
    return (short)(r >> 16);
}
static __device__ __forceinline__ float bf2f(short s) {
    return __uint_as_float(((unsigned int)(unsigned short)s) << 16);
}

static __device__ __forceinline__ void load_lds16(const void* g, void* l) {
    __builtin_amdgcn_global_load_lds(
        (const __attribute__((address_space(1))) unsigned int*)g,
        (__attribute__((address_space(3))) unsigned int*)l, 16, 0, 0);
}

// ------- fused prep: cast x (f32->bf16) + transpose W_qkv + transpose W_out -------
__global__ __launch_bounds__(256) void prep_kernel(
    const float* __restrict__ x, short* __restrict__ Xb,
    const float* __restrict__ Wqkv, short* __restrict__ Wqkvt,
    const float* __restrict__ Wout, short* __restrict__ Woutt) {
    const int blk = blockIdx.x;
    if (blk < 4096) {
        const int i = blk * 256 + threadIdx.x;
        const float4 v0 = *(const float4*)(x + (size_t)i * 8);
        const float4 v1 = *(const float4*)(x + (size_t)i * 8 + 4);
        short8 s;
        s[0] = f2bf(v0.x); s[1] = f2bf(v0.y); s[2] = f2bf(v0.z); s[3] = f2bf(v0.w);
        s[4] = f2bf(v1.x); s[5] = f2bf(v1.y); s[6] = f2bf(v1.z); s[7] = f2bf(v1.w);
        *(short8*)(Xb + (size_t)i * 8) = s;
        return;
    }
    __shared__ float tile[32][33];
    const float* in;
    short* out;
    int R, C, bx, by;
    if (blk < 16384) {
        const int local = blk - 4096;
        in = Wqkv; out = Wqkvt; R = 2048; C = 6144;
        bx = local % 192; by = local / 192;
    } else {
        const int local = blk - 16384;
        in = Wout; out = Woutt; R = 2048; C = 2048;
        bx = local % 64; by = local / 64;
    }
    const int tx = threadIdx.x & 31, ty = threadIdx.x >> 5;
    const int xx = bx * 32 + tx;
    const int y0 = by * 32;
#pragma unroll
    for (int j = 0; j < 4; ++j)
        tile[ty + j * 8][tx] = in[(size_t)(y0 + ty + j * 8) * C + xx];
    __syncthreads();
#pragma unroll
    for (int j = 0; j < 4; ++j)
        out[(size_t)(bx * 32 + ty + j * 8) * R + y0 + tx] =
            f2bf(tile[tx][ty + j * 8]);
}

// ---- GEMM (BK=64, A-dbuf + B-single, 48 KB LDS): A[M,K] x Bt[N,K] -> C[M,N] ----
// 128x128 tile, 4 waves. Per K-step: issue A(t+1)->other A buf | read bfr |
// lgkmcnt(0)+s_barrier (B reads retired; A-DMA keeps flying) | issue B(t+1) |
// af reads + 32 MFMA | __syncthreads (drains DMA). XOR chunk swizzle
// (physical = logical ^ (row&7)) on staging source and frag reads.
// EPI=0: QKV scatter; V tiles transposed through LDS for coalesced Vt writes.
template <int EPI>
__global__ __launch_bounds__(256) void gemm64_kernel(
    const short* __restrict__ A, const short* __restrict__ Bt,
    const float* __restrict__ bias, float* __restrict__ Cf,
    short* __restrict__ Qb, short* __restrict__ Kb, short* __restrict__ Vt,
    int M, int N, int K, int gx) {
    __shared__ __align__(16) short SMEM[24576];   // 48 KB
    // Abuf0 @0, Abuf1 @8192, Bbuf @16384 (short indices)

    const int tid = threadIdx.x;
    const int lane = tid & 63, wave = tid >> 6;
    const int wm = wave >> 1, wn = wave & 1;
    const int lr = lane & 15, lk = lane >> 4;
    const int swl = lr & 7;                       // read-side swizzle key

    const int nwg = gridDim.x;
    const int id = blockIdx.x;
    const int swz = (id & 7) * (nwg >> 3) + (id >> 3);
    const int bx = swz % gx, by = swz / gx;
    const int bm0 = by * 128, bn0 = bx * 128;

    // staging: 4 issues per matrix; issue j covers chunks g = j*256+tid
    // row = g>>3 (0..127), physical slot g&7 holds logical chunk (g&7)^(row&7)
    const char* aSrc[4];
    const char* bSrc[4];
#pragma unroll
    for (int j = 0; j < 4; ++j) {
        const int g = j * 256 + tid;
        const int row = g >> 3;
        const int ch = (g & 7) ^ (row & 7);
        aSrc[j] = (const char*)(A + (size_t)(bm0 + row) * K + ch * 8);
        bSrc[j] = (const char*)(Bt + (size_t)(bn0 + row) * K + ch * 8);
    }

    floatx4 acc[4][4];
#pragma unroll
    for (int m = 0; m < 4; ++m)
#pragma unroll
        for (int n = 0; n < 4; ++n) acc[m][n] = (floatx4){0.f, 0.f, 0.f, 0.f};

    const int nt = K >> 6;   // BK=64

    // prologue: stage A(0)->Abuf0, B(0)->Bbuf
#pragma unroll
    for (int j = 0; j < 4; ++j) {
        load_lds16(aSrc[j], &SMEM[(j * 256 + tid) * 8]);
        load_lds16(bSrc[j], &SMEM[16384 + (j * 256 + tid) * 8]);
    }
    __syncthreads();

    for (int t = 0; t < nt; ++t) {
        const int a = t & 1;
        const size_t ko = (size_t)(t + 1) * 128;   // next K-step byte offset

        if (t + 1 < nt) {  // A(t+1) -> other A buffer; flies the whole iteration
            const int ab = (a ^ 1) * 8192;
#pragma unroll
            for (int j = 0; j < 4; ++j)
                load_lds16(aSrc[j] + ko, &SMEM[ab + (j * 256 + tid) * 8]);
        }

        // B fragments for this K-step
        short8 bfr[4][2];
#pragma unroll
        for (int n = 0; n < 4; ++n)
#pragma unroll
            for (int ks = 0; ks < 2; ++ks)
                bfr[n][ks] = *(const short8*)
                    &SMEM[16384 + (wn * 64 + n * 16 + lr) * 64 +
                          (((ks * 4 + lk) ^ swl) * 8)];

        // barA: B reads retired block-wide; vmcnt NOT drained (A-DMA flying)
        __builtin_amdgcn_sched_barrier(0);
        asm volatile("s_waitcnt lgkmcnt(0)" ::: "memory");
        __builtin_amdgcn_sched_barrier(0);
        __builtin_amdgcn_s_barrier();

        if (t + 1 < nt) {  // B(t+1): overwrites Bbuf; flies over the MFMA phase
#pragma unroll
            for (int j = 0; j < 4; ++j)
                load_lds16(bSrc[j] + ko, &SMEM[16384 + (j * 256 + tid) * 8]);
        }

        const short* Ac = SMEM + a * 8192;
        short8 af[4][2];
#pragma unroll
        for (int m = 0; m < 4; ++m)
#pragma unroll
            for (int ks = 0; ks < 2; ++ks)
                af[m][ks] = *(const short8*)
                    &Ac[(wm * 64 + m * 16 + lr) * 64 + (((ks * 4 + lk) ^ swl) * 8)];
        __builtin_amdgcn_s_setprio(1);
#pragma unroll
        for (int m = 0; m < 4; ++m)
#pragma unroll
            for (int n = 0; n < 4; ++n) {
                acc[m][n] = __builtin_amdgcn_mfma_f32_16x16x32_bf16(
                    af[m][0], bfr[n][0], acc[m][n], 0, 0, 0);
                acc[m][n] = __builtin_amdgcn_mfma_f32_16x16x32_bf16(
                    af[m][1], bfr[n][1], acc[m][n], 0, 0, 0);
            }
        __builtin_amdgcn_s_setprio(0);

        __syncthreads();   // drains A(t+1)+B(t+1) DMA; retires af reads
    }

    // ---- epilogue ----
    if (EPI == 1) {
#pragma unroll
        for (int m = 0; m < 4; ++m)
#pragma unroll
            for (int n = 0; n < 4; ++n)
#pragma unroll
                for (int r = 0; r < 4; ++r) {
                    const int row = bm0 + wm * 64 + m * 16 + lk * 4 + r;
                    const int col = bn0 + wn * 64 + n * 16 + lr;
                    Cf[(size_t)row * N + col] = acc[m][n][r] + bias[col];
                }
    } else {
        const int sec = bn0 >> 11;           // 0=Q 1=K 2=V, uniform per block
        if (sec == 2) {
            // V: transpose through LDS, then coalesced 16B writes to Vt[dq][s]
            __syncthreads();
            short* Vtile = SMEM;             // needs 34.8 KB < 48 KB (SMEM dead)
#pragma unroll
            for (int m = 0; m < 4; ++m)
#pragma unroll
                for (int n = 0; n < 4; ++n)
#pragma unroll
                    for (int r = 0; r < 4; ++r) {
                        const int lrow = wm * 64 + m * 16 + lk * 4 + r;  // s-local
                        const int c = wn * 64 + n * 16 + lr;             // dq
                        const float val = acc[m][n][r] + bias[bn0 + c];
                        Vtile[c * 136 + lrow] = f2bf(val);
                    }
            __syncthreads();
            const int b = bm0 >> 11, s0b = bm0 & 2047;
            const int h = (bn0 >> 7) & 15;
            short* Vbase = Vt + (((size_t)(b * 16 + h)) * 128) * 2048 + s0b;
            const int sOff = (tid & 15) * 8;
#pragma unroll
            for (int j = 0; j < 8; ++j) {
                const int dq = (tid >> 4) + 16 * j;
                *(short8*)&Vbase[(size_t)dq * 2048 + sOff] =
                    *(const short8*)&Vtile[dq * 136 + sOff];
            }
        } else {
            short* T = (sec == 0) ? Qb : Kb;
#pragma unroll
            for (int m = 0; m < 4; ++m)
#pragma unroll
                for (int n = 0; n < 4; ++n)
#pragma unroll
                    for (int r = 0; r < 4; ++r) {
                        const int row = bm0 + wm * 64 + m * 16 + lk * 4 + r;
                        const int col = bn0 + wn * 64 + n * 16 + lr;
                        const float val = acc[m][n][r] + bias[col];
                        const int h = (col >> 7) & 15, dq = col & 127;
                        const int b = row >> 11, s = row & 2047;
                        T[(((size_t)(b * 16 + h)) * 2048 + s) * 128 + dq] = f2bf(val);
                    }
        }
    }
}

// ------- RoPE, vectorized: 4 (t1,t2) pairs per thread via short4 loads -------
__global__ void rope_kernel(short* __restrict__ Qb, short* __restrict__ Kb,
                            const int* __restrict__ pos, int total4) {
    int i = blockIdx.x * blockDim.x + threadIdx.x;
    short* T = Qb;
    int j = i;
    float g = 0.08838834764831845f * LOG2E;   // folded into Q only
    if (i >= total4) { T = Kb; j = i - total4; g = 1.0f; }
    if (j >= total4) return;
    const int ih0 = (j & 15) * 4;
    const int s = (j >> 4) & 2047;
    const size_t base = ((size_t)(j >> 4)) * 128 + ih0;
    short4v a = *(const short4v*)&T[base];
    short4v b = *(const short4v*)&T[base + 64];
    const float p = (float)pos[s];
    short4v ra, rb;
#pragma unroll
    for (int k = 0; k < 4; ++k) {
        const float ang = p * exp2f((float)(ih0 + k) * (-13.287712379549449f / 64.0f));
        float sn, cs;
        __sincosf(ang, &sn, &cs);
        sn *= g; cs *= g;
        const float t1 = bf2f(a[k]), t2 = bf2f(b[k]);
        ra[k] = f2bf(t1 * cs - t2 * sn);
        rb[k] = f2bf(t1 * sn + t2 * cs);
    }
    *(short4v*)&T[base] = ra;
    *(short4v*)&T[base + 64] = rb;
}

// ---------------- causal flash attention v8: QBLK=128, 8 waves ----------------
// KVBLK=64, single-buffered K/V in LDS (51 KB), 2 barriers/tile (v6 schedule).
// Grid 512 = 2 blocks/CU; per-XCD long/short pairing; 4 heads per XCD.
__global__ __launch_bounds__(512) void attn_kernel(
    const short* __restrict__ Qb, const short* __restrict__ Kb,
    const short* __restrict__ Vt, short* __restrict__ Ob) {
    const int f = blockIdx.x;                    // 512 blocks
    const int xcd = f & 7;
    const int rank = f >> 3;
    const int s_idx = (rank < 32) ? rank : 95 - rank;
    const int qt = 15 - (s_idx >> 2);
    const int bh = xcd * 4 + (s_idx & 3);
    const int tid = threadIdx.x;
    const int wave = tid >> 6, lane = tid & 63;
    const int lr = lane & 15, lk = lane >> 4;
    const int q0 = qt * 128;
    const short* Qh = Qb + (size_t)bh * 2048 * 128;
    const short* Kh = Kb + (size_t)bh * 2048 * 128;
    const short* Vh = Vt + (size_t)bh * 128 * 2048;

    __shared__ __align__(16) short Ks[64 * 128];
    __shared__ __align__(16) short Vs[128 * 64];
    __shared__ __align__(16) short Ps[8][16][72];

    const int c0 = tid, c1 = tid + 512;
    const int rK0 = c0 >> 4, rK1 = c1 >> 4;
    const int rV0 = c0 >> 3, rV1 = c1 >> 3;
    const char* srcK0 = (const char*)Kh + (size_t)rK0 * 256 + (((c0 & 15) ^ (rK0 & 7)) * 16);
    const char* srcK1 = (const char*)Kh + (size_t)rK1 * 256 + (((c1 & 15) ^ (rK1 & 7)) * 16);
    const char* srcV0 = (const char*)Vh + (size_t)rV0 * 4096 + (((c0 & 7) ^ (rV0 & 7)) * 16);
    const char* srcV1 = (const char*)Vh + (size_t)rV1 * 4096 + (((c1 & 7) ^ (rV1 & 7)) * 16);
    char* dK0 = (char*)Ks + c0 * 16;
    char* dK1 = (char*)Ks + c1 * 16;
    char* dV0 = (char*)Vs + c0 * 16;
    char* dV1 = (char*)Vs + c1 * 16;

    short8 qf[4];
#pragma unroll
    for (int kc = 0; kc < 4; ++kc)
        qf[kc] = *(const short8*)&Qh[(size_t)(q0 + wave * 16 + lr) * 128 + kc * 32 + lk * 8];

    floatx4 o[8];
#pragma unroll
    for (int d = 0; d < 8; ++d) o[d] = (floatx4){0.f, 0.f, 0.f, 0.f};
    float mrow[4], lrow[4];
#pragma unroll
    for (int r = 0; r < 4; ++r) { mrow[r] = -3.0e38f; lrow[r] = 0.f; }

    const int nkt = 2 * qt + 2;
    const int swzk = (lr & 7) << 3;

    load_lds16(srcK0, dK0);
    load_lds16(srcK1, dK1);
    load_lds16(srcV0, dV0);
    load_lds16(srcV1, dV1);
    __syncthreads();

    for (int t = 0; t < nkt; ++t) {
        const int s0 = t * 64;
        const bool active = !(t == nkt - 1 && wave < 4);

        floatx4 sv[4];
        if (active) {
            __builtin_amdgcn_s_setprio(1);
#pragma unroll
            for (int nt = 0; nt < 4; ++nt) {
                floatx4 a = (floatx4){0.f, 0.f, 0.f, 0.f};
#pragma unroll
                for (int kc = 0; kc < 4; ++kc) {
                    short8 kf = *(const short8*)
                        &Ks[(nt * 16 + lr) * 128 + ((kc * 32 + lk * 8) ^ swzk)];
                    a = __builtin_amdgcn_mfma_f32_16x16x32_bf16(qf[kc], kf, a, 0, 0, 0);
                }
                sv[nt] = a;
            }
            __builtin_amdgcn_s_setprio(0);
        }

        __syncthreads();
        if (t + 1 < nkt) {
            const size_t offK = (size_t)(t + 1) * 16384;
            load_lds16(srcK0 + offK, dK0);
            load_lds16(srcK1 + offK, dK1);
        }

        if (active) {
            if (t >= nkt - 2) {
#pragma unroll
                for (int nt = 0; nt < 4; ++nt)
#pragma unroll
                    for (int r = 0; r < 4; ++r) {
                        const int col = s0 + nt * 16 + lr;
                        const int row = q0 + wave * 16 + lk * 4 + r;
                        if (col > row) sv[nt][r] = -3.0e38f;
                    }
            }

            float tm[4];
#pragma unroll
            for (int r = 0; r < 4; ++r) {
                float v = fmaxf(fmaxf(sv[0][r], sv[1][r]), fmaxf(sv[2][r], sv[3][r]));
                v = fmaxf(v, __shfl_xor(v, 1));
                v = fmaxf(v, __shfl_xor(v, 2));
                v = fmaxf(v, __shfl_xor(v, 4));
                v = fmaxf(v, __shfl_xor(v, 8));
                tm[r] = v;
            }

            const bool ok = (tm[0] <= mrow[0] + 8.f) && (tm[1] <= mrow[1] + 8.f) &&
                            (tm[2] <= mrow[2] + 8.f) && (tm[3] <= mrow[3] + 8.f);
            if (!__all(ok)) {
                float alpha[4];
#pragma unroll
                for (int r = 0; r < 4; ++r) {
                    const float mn = fmaxf(mrow[r], tm[r]);
                    alpha[r] = exp2f(mrow[r] - mn);
                    mrow[r] = mn;
                    lrow[r] *= alpha[r];
                }
#pragma unroll
                for (int d = 0; d < 8; ++d)
#pragma unroll
                    for (int r = 0; r < 4; ++r) o[d][r] *= alpha[r];
            }

#pragma unroll
            for (int r = 0; r < 4; ++r) {
                float rs = 0.f;
#pragma unroll
                for (int nt = 0; nt < 4; ++nt) {
                    const float p = exp2f(sv[nt][r] - mrow[r]);
                    sv[nt][r] = p;
                    rs += p;
                }
                lrow[r] += rs;
            }
#pragma unroll
            for (int nt = 0; nt < 4; ++nt)
#pragma unroll
                for (int r = 0; r < 4; ++r)
                    Ps[wave][lk * 4 + r][nt * 16 + lr] =
                        (short)(__float_as_uint(sv[nt][r]) >> 16);

            __builtin_amdgcn_s_setprio(1);
#pragma unroll
            for (int kc = 0; kc < 2; ++kc) {
                short8 pf = *(const short8*)&Ps[wave][lr][kc * 32 + lk * 8];
#pragma unroll
                for (int d = 0; d < 8; ++d) {
                    short8 vf = *(const short8*)
                        &Vs[(d * 16 + lr) * 64 + ((kc * 32 + lk * 8) ^ swzk)];
                    o[d] = __builtin_amdgcn_mfma_f32_16x16x32_bf16(pf, vf, o[d], 0, 0, 0);
                }
            }
            __builtin_amdgcn_s_setprio(0);
        }

        if (t + 1 < nkt) {
            __syncthreads();
            const size_t offV = (size_t)(t + 1) * 128;
            load_lds16(srcV0 + offV, dV0);
            load_lds16(srcV1 + offV, dV1);
        }
    }

    // ---- epilogue ----
    float linv[4];
#pragma unroll
    for (int r = 0; r < 4; ++r) {
        float l = lrow[r];
        l += __shfl_xor(l, 1);
        l += __shfl_xor(l, 2);
        l += __shfl_xor(l, 4);
        l += __shfl_xor(l, 8);
        linv[r] = 1.0f / l;
    }
    const int b = bh >> 4, h = bh & 15;
#pragma unroll
    for (int d = 0; d < 8; ++d)
#pragma unroll
        for (int r = 0; r < 4; ++r) {
            const int srow = q0 + wave * 16 + lk * 4 + r;
            const float val = o[d][r] * linv[r];
            Ob[((size_t)(b * 2048 + srow)) * 2048 + h * 128 + d * 16 + lr] = f2bf(val);
        }
}

extern "C" void kernel_launch(void* const* d_in, const int* in_sizes, int n_in,
                              void* d_out, int out_size, void* d_ws, size_t ws_size,
                              hipStream_t stream) {
    const float* x = (const float*)d_in[0];
    const int* rope_pos = (const int*)d_in[1];
    const float* W_qkv = (const float*)d_in[2];
    const float* b_qkv = (const float*)d_in[3];
    const float* W_out = (const float*)d_in[4];
    const float* b_out = (const float*)d_in[5];
    float* out = (float*)d_out;

    char* ws = (char*)d_ws;
    short* Wqkvt = (short*)ws;                                   // 25165824 B
    short* Woutt = (short*)(ws + 25165824);                      // 8388608 B
    short* Qb = (short*)(ws + 25165824 + 8388608);               // 8388608 B each
    short* Kb = Qb + 8388608;
    short* Vt = Kb + 8388608;
    short* Attn = Vt + 8388608;
    short* Xb = Attn;  // alias: Xb dead before attn_kernel writes Attn

    prep_kernel<<<20480, 256, 0, stream>>>(x, Xb, W_qkv, Wqkvt, W_out, Woutt);
    gemm64_kernel<0><<<1536, 256, 0, stream>>>(
        Xb, Wqkvt, b_qkv, nullptr, Qb, Kb, Vt, 4096, 6144, 2048, 48);
    rope_kernel<<<8192, 256, 0, stream>>>(Qb, Kb, rope_pos, 1048576);
    attn_kernel<<<512, 512, 0, stream>>>(Qb, Kb, Vt, Attn);
    gemm64_kernel<1><<<512, 256, 0, stream>>>(
        Attn, Woutt, b_out, out, nullptr, nullptr, nullptr, 4096, 2048, 2048, 16);
}